// Round 26
// baseline (151.035 us; speedup 1.0000x reference)
//
#include <hip/hip_runtime.h>
#include <hip/hip_bf16.h>

#define NN 50000
#define NE 400000
#define NT 3125   // NN/16 row tiles

typedef unsigned short u16;
typedef short short8 __attribute__((ext_vector_type(8)));
typedef float f32x4 __attribute__((ext_vector_type(4)));

__device__ __forceinline__ float geluf(float x){ return 0.5f*x*(1.0f+erff(x*0.70710678118654752440f)); }
__device__ __forceinline__ u16 f2bfb(float f){
  union { __hip_bfloat16 h; u16 u; } cv; cv.h = __float2bfloat16(f); return cv.u;
}
__device__ __forceinline__ float bfb2f(u16 u){ return __uint_as_float(((unsigned)u)<<16); }

// ---- zero deg+cur (400,384 B = 25,024 int4) ----
__global__ __launch_bounds__(256) void k_zero(int4* __restrict__ p){
  int i = blockIdx.x*256 + threadIdx.x;
  if (i < 25024) p[i] = (int4){0,0,0,0};
}

// ---- K0: blocks 0..31 cvt W1|WA (row-major); 32..47 build W2r (fragment-ordered); 48+ hist ----
__global__ __launch_bounds__(256) void k_pre(const float* __restrict__ W1,
    const float* __restrict__ WA, const float* __restrict__ W2,
    u16* __restrict__ W1b, u16* __restrict__ WAb, u16* __restrict__ W2r,
    const int* __restrict__ dst, int* __restrict__ deg)
{
  if (blockIdx.x < 32){
    int i4 = (blockIdx.x*256 + threadIdx.x) * 4;   // [0, 32768)
    const float* srcp; u16* dstp; int off;
    if (i4 < 16384){ srcp = W1; dstp = W1b; off = i4; }
    else { srcp = WA; dstp = WAb; off = i4 - 16384; }
    float4 v = *(const float4*)(srcp + off);
    ushort4 o;
    o.x = f2bfb(v.x); o.y = f2bfb(v.y); o.z = f2bfb(v.z); o.w = f2bfb(v.w);
    *(ushort4*)(dstp + off) = o;
  } else if (blockIdx.x < 48){
    int t0 = (blockIdx.x - 32)*2048 + threadIdx.x*8;   // [0, 32768)
    int lane = (t0 >> 3) & 63;
    int kk   = (t0 >> 9) & 7;
    int nb   = t0 >> 12;
    int src  = (nb*16 + (lane & 15))*256 + kk*32 + (lane >> 4)*8;
    float4 v0 = *(const float4*)(W2 + src);
    float4 v1 = *(const float4*)(W2 + src + 4);
    ushort4 o0, o1;
    o0.x = f2bfb(v0.x); o0.y = f2bfb(v0.y); o0.z = f2bfb(v0.z); o0.w = f2bfb(v0.w);
    o1.x = f2bfb(v1.x); o1.y = f2bfb(v1.y); o1.z = f2bfb(v1.z); o1.w = f2bfb(v1.w);
    *(ushort4*)(W2r + t0)     = o0;
    *(ushort4*)(W2r + t0 + 4) = o1;
  } else {
    int e = (blockIdx.x - 48)*256 + threadIdx.x;
    if (e < NE) atomicAdd(&deg[dst[e]], 1);
  }
}

// ---- 512-thread exclusive scan of deg -> offs (run by one block of k_ff1n) ----
__device__ void scan512(const int* __restrict__ deg, int* __restrict__ offs){
  __shared__ int wsum[8];
  __shared__ int sbase_s;
  const int tid = threadIdx.x, lane = tid & 63, wave = tid >> 6;  // 8 waves
  if (tid == 0) sbase_s = 0;
  __syncthreads();
  for (int base = 0; base < NN; base += 2048){
    int i0 = base + tid*4;
    int v0=0,v1=0,v2=0,v3=0;
    if (i0+3 < NN){ int4 v = *(const int4*)(deg+i0); v0=v.x;v1=v.y;v2=v.z;v3=v.w; }
    else {
      if (i0   < NN) v0 = deg[i0];
      if (i0+1 < NN) v1 = deg[i0+1];
      if (i0+2 < NN) v2 = deg[i0+2];
    }
    int own = v0+v1+v2+v3;
    int inc = own;
    #pragma unroll
    for (int s=1;s<64;s<<=1){ int t = __shfl_up(inc, s, 64); if (lane >= s) inc += t; }
    if (lane == 63) wsum[wave] = inc;
    __syncthreads();
    if (wave == 0 && lane < 8){
      int w = wsum[lane];
      #pragma unroll
      for (int s=1;s<8;s<<=1){ int t = __shfl_up(w, s, 64); if (lane >= s) w += t; }
      wsum[lane] = w;
    }
    __syncthreads();
    int sbase = sbase_s;
    int wbase = sbase + (wave ? wsum[wave-1] : 0);
    int excl = wbase + inc - own;
    if (i0   < NN) offs[i0]   = excl;
    if (i0+1 < NN) offs[i0+1] = excl + v0;
    if (i0+2 < NN) offs[i0+2] = excl + v0+v1;
    if (i0+3 < NN) offs[i0+3] = excl + v0+v1+v2;
    __syncthreads();
    if (tid == 0) sbase_s = sbase + wsum[7];
    __syncthreads();
  }
  if (tid == 0) offs[NN] = sbase_s;
}

// ---- K1 fused + scan rider: blocks 0..n-2 do ff1n; block n-1 does scan ----
__global__ __launch_bounds__(512) void k_ff1n(const float* __restrict__ X,
    const u16* __restrict__ W1b, const float* __restrict__ b1,
    const u16* __restrict__ WAb, const float* __restrict__ WB,
    u16* __restrict__ Hb, float* __restrict__ T,
    const int* __restrict__ deg, int* __restrict__ offs)
{
  if (blockIdx.x == gridDim.x - 1){
    scan512(deg, offs);
    return;
  }
  extern __shared__ u16 smem[];
  u16* w1s = smem;                 // [128][136]
  u16* was = smem + 17408;         // [128][136]
  const int LDW = 136;
  for (int idx8 = threadIdx.x*8; idx8 < 128*128; idx8 += 512*8){
    int c = idx8 >> 7, k = idx8 & 127;
    *(short8*)&w1s[c*LDW + k] = *(const short8*)(W1b + idx8);
    *(short8*)&was[c*LDW + k] = *(const short8*)(WAb + idx8);
  }
  __syncthreads();
  const int lane = threadIdx.x & 63;
  const int wave = threadIdx.x >> 6;
  const int lrow = lane & 15;
  const int kgrp = lane >> 4;
  u16* hls = smem + 34816 + wave*(16*LDW);   // per-wave [16][136]
  float4 b1v[8];
  #pragma unroll
  for (int nb = 0; nb < 8; nb++) b1v[nb] = *(const float4*)(b1 + nb*16 + kgrp*4);
  float wbv[4][8];
  #pragma unroll
  for (int m = 0; m < 4; m++)
    #pragma unroll
    for (int nb = 0; nb < 8; nb++)
      wbv[m][nb] = WB[m*128 + nb*16 + lrow];
  const int nffb = gridDim.x - 1;
  for (int tile = blockIdx.x*8 + wave; tile < NT; tile += nffb*8){
    const float* xr = X + (size_t)(tile*16 + lrow)*128 + kgrp*8;
    f32x4 acc[8];
    #pragma unroll
    for (int nb = 0; nb < 8; nb++) acc[nb] = (f32x4){0.f,0.f,0.f,0.f};
    #pragma unroll
    for (int kk = 0; kk < 4; kk++){
      float4 xa = *(const float4*)(xr + kk*32);
      float4 xb = *(const float4*)(xr + kk*32 + 4);
      union { short8 v; u16 u[8]; } af;
      af.u[0]=f2bfb(xa.x); af.u[1]=f2bfb(xa.y); af.u[2]=f2bfb(xa.z); af.u[3]=f2bfb(xa.w);
      af.u[4]=f2bfb(xb.x); af.u[5]=f2bfb(xb.y); af.u[6]=f2bfb(xb.z); af.u[7]=f2bfb(xb.w);
      #pragma unroll
      for (int nb = 0; nb < 8; nb++){
        short8 bf = *(const short8*)&w1s[(nb*16 + lrow)*LDW + kk*32 + kgrp*8];
        acc[nb] = __builtin_amdgcn_mfma_f32_16x16x32_bf16(bf, af.v, acc[nb], 0, 0, 0);
      }
    }
    const size_t rb = (size_t)(tile*16 + lrow)*128 + kgrp*4;
    #pragma unroll
    for (int nb = 0; nb < 8; nb++){
      ushort4 hp;
      #pragma unroll
      for (int r = 0; r < 4; r++)
        ((u16*)&hp)[r] = f2bfb(geluf(acc[nb][r] + b1v[nb][r]));
      *(ushort4*)(Hb + rb + nb*16) = hp;
      *(ushort4*)&hls[lrow*LDW + nb*16 + kgrp*4] = hp;
    }
    f32x4 acc2[8];
    #pragma unroll
    for (int nb = 0; nb < 8; nb++) acc2[nb] = (f32x4){0.f,0.f,0.f,0.f};
    #pragma unroll
    for (int kk = 0; kk < 4; kk++){
      short8 af = *(const short8*)&hls[lrow*LDW + kk*32 + kgrp*8];
      #pragma unroll
      for (int nb = 0; nb < 8; nb++){
        short8 bf = *(const short8*)&was[(nb*16 + lrow)*LDW + kk*32 + kgrp*8];
        acc2[nb] = __builtin_amdgcn_mfma_f32_16x16x32_bf16(af, bf, acc2[nb], 0, 0, 0);
      }
    }
    float part[4][4];
    #pragma unroll
    for (int r = 0; r < 4; r++)
      #pragma unroll
      for (int m = 0; m < 4; m++) part[r][m] = 0.f;
    #pragma unroll
    for (int nb = 0; nb < 8; nb++){
      float g0 = geluf(acc2[nb][0]), g1 = geluf(acc2[nb][1]);
      float g2 = geluf(acc2[nb][2]), g3 = geluf(acc2[nb][3]);
      #pragma unroll
      for (int m = 0; m < 4; m++){
        float w = wbv[m][nb];
        part[0][m] += g0*w; part[1][m] += g1*w;
        part[2][m] += g2*w; part[3][m] += g3*w;
      }
    }
    #pragma unroll
    for (int s = 1; s < 16; s <<= 1)
      #pragma unroll
      for (int r = 0; r < 4; r++)
        #pragma unroll
        for (int m = 0; m < 4; m++)
          part[r][m] += __shfl_xor(part[r][m], s, 64);
    if (lrow == 0){
      #pragma unroll
      for (int r = 0; r < 4; r++){
        f32x4 tv = { part[r][0], part[r][1], part[r][2], part[r][3] };
        *(f32x4*)&T[(size_t)(tile*16 + kgrp*4 + r)*4] = tv;
      }
    }
  }
}

__global__ void k_fill(const int* __restrict__ src, const int* __restrict__ dst,
                       const int* __restrict__ offs, int* __restrict__ cur,
                       int* __restrict__ slist){
  int e = blockIdx.x*256 + threadIdx.x;
  if (e < NE){
    int d = dst[e];
    int p = atomicAdd(&cur[d], 1);
    slist[offs[d] + p] = src[e];
  }
}

// ------- K2b: per-node aggregation; scalarized (SGPR) edge indices -------
__global__ __launch_bounds__(256) void k_agg(const u16* __restrict__ Hb,
    const float* __restrict__ T, const int* __restrict__ offs,
    const int* __restrict__ slist, u16* __restrict__ GAb)
{
  const int lane = threadIdx.x & 63;
  const int wave = threadIdx.x >> 6;
  const int vo = lane*2;
  for (int v = blockIdx.x*4 + wave; v < NN; v += gridDim.x*4){
    const int e0 = __builtin_amdgcn_readfirstlane(offs[v]);
    const int e1 = __builtin_amdgcn_readfirstlane(offs[v+1]);
    float ax0=0, ax1=0, ax2=0, ax3=0;
    float ay0=0, ay1=0, ay2=0, ay3=0;
    float s0=0, s1=0, s2=0, s3=0;
    int idx = e0;
    for (; idx + 8 <= e1; idx += 8){
      unsigned pk[8]; float4 tt[8];
      #pragma unroll
      for (int u = 0; u < 8; u++){
        int sn = slist[idx+u];
        pk[u] = *(const unsigned*)(Hb + (size_t)sn*128 + vo);
        tt[u] = *(const float4*)(T + (size_t)sn*4);
      }
      #pragma unroll
      for (int u = 0; u < 8; u++){
        float hx = bfb2f((u16)(pk[u] & 0xffffu));
        float hy = bfb2f((u16)(pk[u] >> 16));
        ax0 += hx*tt[u].x; ax1 += hx*tt[u].y; ax2 += hx*tt[u].z; ax3 += hx*tt[u].w;
        ay0 += hy*tt[u].x; ay1 += hy*tt[u].y; ay2 += hy*tt[u].z; ay3 += hy*tt[u].w;
        s0 += tt[u].x; s1 += tt[u].y; s2 += tt[u].z; s3 += tt[u].w;
      }
    }
    for (; idx + 4 <= e1; idx += 4){
      unsigned pk[4]; float4 tt[4];
      #pragma unroll
      for (int u = 0; u < 4; u++){
        int sn = slist[idx+u];
        pk[u] = *(const unsigned*)(Hb + (size_t)sn*128 + vo);
        tt[u] = *(const float4*)(T + (size_t)sn*4);
      }
      #pragma unroll
      for (int u = 0; u < 4; u++){
        float hx = bfb2f((u16)(pk[u] & 0xffffu));
        float hy = bfb2f((u16)(pk[u] >> 16));
        ax0 += hx*tt[u].x; ax1 += hx*tt[u].y; ax2 += hx*tt[u].z; ax3 += hx*tt[u].w;
        ay0 += hy*tt[u].x; ay1 += hy*tt[u].y; ay2 += hy*tt[u].z; ay3 += hy*tt[u].w;
        s0 += tt[u].x; s1 += tt[u].y; s2 += tt[u].z; s3 += tt[u].w;
      }
    }
    for (; idx < e1; idx++){
      int sn = slist[idx];
      unsigned pk = *(const unsigned*)(Hb + (size_t)sn*128 + vo);
      float hx = bfb2f((u16)(pk & 0xffffu));
      float hy = bfb2f((u16)(pk >> 16));
      float4 wt = *(const float4*)(T + (size_t)sn*4);
      ax0 += hx*wt.x; ax1 += hx*wt.y; ax2 += hx*wt.z; ax3 += hx*wt.w;
      ay0 += hy*wt.x; ay1 += hy*wt.y; ay2 += hy*wt.z; ay3 += hy*wt.w;
      s0 += wt.x; s1 += wt.y; s2 += wt.z; s3 += wt.w;
    }
    float inv = 1.0f / fmaxf((float)(e1 - e0), 1.0f);
    float ox = geluf(ax0)*s0 + geluf(ax1)*s1 + geluf(ax2)*s2 + geluf(ax3)*s3;
    float oy = geluf(ay0)*s0 + geluf(ay1)*s1 + geluf(ay2)*s2 + geluf(ay3)*s3;
    ushort2 res;
    res.x = f2bfb(geluf(ox * inv));
    res.y = f2bfb(geluf(oy * inv));
    *(ushort2*)(GAb + (size_t)v*128 + vo) = res;
  }
}

// ------- K3 (MFMA, LDS-free, half-per-BLOCK for L1 reuse): out = [GAb, gelu(Hb)] @ W2^T + b2 -------
__global__ __launch_bounds__(256, 4) void k_ff2(const u16* __restrict__ GAb,
    const u16* __restrict__ Hb, const u16* __restrict__ W2r,
    const float* __restrict__ b2, float* __restrict__ out)
{
  const int lane = threadIdx.x & 63;
  const int wave = threadIdx.x >> 6;      // 0..3
  const int lrow = lane & 15;
  const int kgrp = lane >> 4;
  const int nbh  = (blockIdx.x & 1)*4;    // which 4 nb-blocks (64 output cols) — same for whole block
  const int tile = (blockIdx.x >> 1)*4 + wave;
  if (tile >= NT) return;
  const int row = tile*16 + lrow;
  short8 a[8];
  {
    const u16* ga = GAb + (size_t)row*128 + kgrp*8;
    const u16* hb = Hb  + (size_t)row*128 + kgrp*8;
    #pragma unroll
    for (int kk = 0; kk < 4; kk++){
      a[kk]   = *(const short8*)(ga + kk*32);
      a[4+kk] = *(const short8*)(hb + kk*32);
    }
    #pragma unroll
    for (int kk = 4; kk < 8; kk++){
      union { short8 v; u16 u[8]; } g;
      #pragma unroll
      for (int j = 0; j < 8; j++)
        g.u[j] = f2bfb(geluf(bfb2f(((const u16*)&a[kk])[j])));
      a[kk] = g.v;
    }
  }
  f32x4 acc[4];
  #pragma unroll
  for (int q = 0; q < 4; q++) acc[q] = (f32x4){0.f,0.f,0.f,0.f};
  const u16* wbase = W2r + lane*8;
  #pragma unroll
  for (int kk = 0; kk < 8; kk++){
    #pragma unroll
    for (int q = 0; q < 4; q++){
      short8 bf = *(const short8*)(wbase + (size_t)((nbh + q)*8 + kk)*512);
      acc[q] = __builtin_amdgcn_mfma_f32_16x16x32_bf16(bf, a[kk], acc[q], 0, 0, 0);
    }
  }
  float* orp = out + (size_t)row*128 + nbh*16 + kgrp*4;
  #pragma unroll
  for (int q = 0; q < 4; q++){
    float4 bv = *(const float4*)(b2 + (nbh + q)*16 + kgrp*4);
    f32x4 o;
    o[0] = acc[q][0] + bv.x;
    o[1] = acc[q][1] + bv.y;
    o[2] = acc[q][2] + bv.z;
    o[3] = acc[q][3] + bv.w;
    *(f32x4*)(orp + q*16) = o;
  }
}

extern "C" void kernel_launch(void* const* d_in, const int* in_sizes, int n_in,
                              void* d_out, int out_size, void* d_ws, size_t ws_size,
                              hipStream_t stream)
{
  (void)in_sizes; (void)n_in; (void)out_size; (void)ws_size;
  const float* X  = (const float*)d_in[0];
  const int*   ei = (const int*)d_in[1];
  const float* W1 = (const float*)d_in[2];
  const float* b1 = (const float*)d_in[3];
  const float* WA = (const float*)d_in[4];
  const float* WB = (const float*)d_in[5];
  const float* W2 = (const float*)d_in[6];
  const float* b2 = (const float*)d_in[7];
  float* out = (float*)d_out;
  const int* src = ei;
  const int* dst = ei + NE;

  char* p = (char*)d_ws;
  u16*   Hb   = (u16*)(p);                 // 12,800,000 B
  u16*   GAb  = (u16*)(p + 12800000);      // 12,800,000 B
  float* T    = (float*)(p + 25600000);    //    800,000 B
  int*   deg  = (int*)(p + 26400000);      //    200,192 B
  int*   cur  = (int*)(p + 26600192);      //    200,192 B  (deg+cur zeroed by k_zero)
  int*   offs = (int*)(p + 26800384);      //    200,448 B
  int*   slist= (int*)(p + 27000832);      //  1,600,000 B
  u16*   W1b  = (u16*)(p + 28600832);      //     32,768 B
  u16*   WAb  = (u16*)(p + 28633600);      //     32,768 B
  u16*   W2r  = (u16*)(p + 28666368);      //     65,536 B  (total ~28.7 MB)

  (void)hipFuncSetAttribute((const void*)k_ff1n, hipFuncAttributeMaxDynamicSharedMemorySize, 104448);

  k_zero<<<98, 256, 0, stream>>>((int4*)deg);
  k_pre <<<48 + (NE+255)/256, 256, 0, stream>>>(W1, WA, W2, W1b, WAb, W2r, dst, deg);
  k_ff1n<<<392, 512, 104448, stream>>>(X, W1b, b1, WAb, WB, Hb, T, deg, offs);
  k_fill<<<(NE+255)/256, 256, 0, stream>>>(src, dst, offs, cur, slist);
  k_agg <<<2048, 256, 0, stream>>>(Hb, T, offs, slist, GAb);
  k_ff2 <<<2*((NT+3)/4), 256, 0, stream>>>(GAb, Hb, W2r, b2, out);
}

// Round 27
// 142.999 us; speedup vs baseline: 1.0562x; 1.0562x over previous
//
#include <hip/hip_runtime.h>
#include <hip/hip_bf16.h>

#define NN 50000
#define NE 400000
#define NT 3125   // NN/16 row tiles

typedef unsigned short u16;
typedef short short8 __attribute__((ext_vector_type(8)));
typedef float f32x4 __attribute__((ext_vector_type(4)));

__device__ __forceinline__ float geluf(float x){ return 0.5f*x*(1.0f+erff(x*0.70710678118654752440f)); }
__device__ __forceinline__ u16 f2bfb(float f){
  union { __hip_bfloat16 h; u16 u; } cv; cv.h = __float2bfloat16(f); return cv.u;
}
__device__ __forceinline__ float bfb2f(u16 u){ return __uint_as_float(((unsigned)u)<<16); }

// ---- zero deg+cur (400,384 B = 25,024 int4) ----
__global__ __launch_bounds__(256) void k_zero(int4* __restrict__ p){
  int i = blockIdx.x*256 + threadIdx.x;
  if (i < 25024) p[i] = (int4){0,0,0,0};
}

// ---- K0: blocks 0..31 cvt W1|WA (row-major); 32..47 build W2r (fragment-ordered); 48+ hist ----
__global__ __launch_bounds__(256) void k_pre(const float* __restrict__ W1,
    const float* __restrict__ WA, const float* __restrict__ W2,
    u16* __restrict__ W1b, u16* __restrict__ WAb, u16* __restrict__ W2r,
    const int* __restrict__ dst, int* __restrict__ deg)
{
  if (blockIdx.x < 32){
    int i4 = (blockIdx.x*256 + threadIdx.x) * 4;   // [0, 32768)
    const float* srcp; u16* dstp; int off;
    if (i4 < 16384){ srcp = W1; dstp = W1b; off = i4; }
    else { srcp = WA; dstp = WAb; off = i4 - 16384; }
    float4 v = *(const float4*)(srcp + off);
    ushort4 o;
    o.x = f2bfb(v.x); o.y = f2bfb(v.y); o.z = f2bfb(v.z); o.w = f2bfb(v.w);
    *(ushort4*)(dstp + off) = o;
  } else if (blockIdx.x < 48){
    int t0 = (blockIdx.x - 32)*2048 + threadIdx.x*8;   // [0, 32768)
    int lane = (t0 >> 3) & 63;
    int kk   = (t0 >> 9) & 7;
    int nb   = t0 >> 12;
    int src  = (nb*16 + (lane & 15))*256 + kk*32 + (lane >> 4)*8;
    float4 v0 = *(const float4*)(W2 + src);
    float4 v1 = *(const float4*)(W2 + src + 4);
    ushort4 o0, o1;
    o0.x = f2bfb(v0.x); o0.y = f2bfb(v0.y); o0.z = f2bfb(v0.z); o0.w = f2bfb(v0.w);
    o1.x = f2bfb(v1.x); o1.y = f2bfb(v1.y); o1.z = f2bfb(v1.z); o1.w = f2bfb(v1.w);
    *(ushort4*)(W2r + t0)     = o0;
    *(ushort4*)(W2r + t0 + 4) = o1;
  } else {
    int e = (blockIdx.x - 48)*256 + threadIdx.x;
    if (e < NE) atomicAdd(&deg[dst[e]], 1);
  }
}

// ---- K1 fused (512-thread proven form): Hb = bf16(gelu(X@W1^T+b1)); T = gelu(H@WA^T)@WB^T ----
__global__ __launch_bounds__(512) void k_ff1n(const float* __restrict__ X,
    const u16* __restrict__ W1b, const float* __restrict__ b1,
    const u16* __restrict__ WAb, const float* __restrict__ WB,
    u16* __restrict__ Hb, float* __restrict__ T)
{
  extern __shared__ u16 smem[];
  u16* w1s = smem;                 // [128][136]
  u16* was = smem + 17408;         // [128][136]
  const int LDW = 136;
  for (int idx8 = threadIdx.x*8; idx8 < 128*128; idx8 += 512*8){
    int c = idx8 >> 7, k = idx8 & 127;
    *(short8*)&w1s[c*LDW + k] = *(const short8*)(W1b + idx8);
    *(short8*)&was[c*LDW + k] = *(const short8*)(WAb + idx8);
  }
  __syncthreads();
  const int lane = threadIdx.x & 63;
  const int wave = threadIdx.x >> 6;
  const int lrow = lane & 15;
  const int kgrp = lane >> 4;
  u16* hls = smem + 34816 + wave*(16*LDW);   // per-wave [16][136]
  float4 b1v[8];
  #pragma unroll
  for (int nb = 0; nb < 8; nb++) b1v[nb] = *(const float4*)(b1 + nb*16 + kgrp*4);
  float wbv[4][8];
  #pragma unroll
  for (int m = 0; m < 4; m++)
    #pragma unroll
    for (int nb = 0; nb < 8; nb++)
      wbv[m][nb] = WB[m*128 + nb*16 + lrow];
  for (int tile = blockIdx.x*8 + wave; tile < NT; tile += gridDim.x*8){
    const float* xr = X + (size_t)(tile*16 + lrow)*128 + kgrp*8;
    f32x4 acc[8];
    #pragma unroll
    for (int nb = 0; nb < 8; nb++) acc[nb] = (f32x4){0.f,0.f,0.f,0.f};
    #pragma unroll
    for (int kk = 0; kk < 4; kk++){
      float4 xa = *(const float4*)(xr + kk*32);
      float4 xb = *(const float4*)(xr + kk*32 + 4);
      union { short8 v; u16 u[8]; } af;
      af.u[0]=f2bfb(xa.x); af.u[1]=f2bfb(xa.y); af.u[2]=f2bfb(xa.z); af.u[3]=f2bfb(xa.w);
      af.u[4]=f2bfb(xb.x); af.u[5]=f2bfb(xb.y); af.u[6]=f2bfb(xb.z); af.u[7]=f2bfb(xb.w);
      #pragma unroll
      for (int nb = 0; nb < 8; nb++){
        short8 bf = *(const short8*)&w1s[(nb*16 + lrow)*LDW + kk*32 + kgrp*8];
        acc[nb] = __builtin_amdgcn_mfma_f32_16x16x32_bf16(bf, af.v, acc[nb], 0, 0, 0);
      }
    }
    const size_t rb = (size_t)(tile*16 + lrow)*128 + kgrp*4;
    #pragma unroll
    for (int nb = 0; nb < 8; nb++){
      ushort4 hp;
      #pragma unroll
      for (int r = 0; r < 4; r++)
        ((u16*)&hp)[r] = f2bfb(geluf(acc[nb][r] + b1v[nb][r]));
      *(ushort4*)(Hb + rb + nb*16) = hp;
      *(ushort4*)&hls[lrow*LDW + nb*16 + kgrp*4] = hp;
    }
    f32x4 acc2[8];
    #pragma unroll
    for (int nb = 0; nb < 8; nb++) acc2[nb] = (f32x4){0.f,0.f,0.f,0.f};
    #pragma unroll
    for (int kk = 0; kk < 4; kk++){
      short8 af = *(const short8*)&hls[lrow*LDW + kk*32 + kgrp*8];
      #pragma unroll
      for (int nb = 0; nb < 8; nb++){
        short8 bf = *(const short8*)&was[(nb*16 + lrow)*LDW + kk*32 + kgrp*8];
        acc2[nb] = __builtin_amdgcn_mfma_f32_16x16x32_bf16(af, bf, acc2[nb], 0, 0, 0);
      }
    }
    float part[4][4];
    #pragma unroll
    for (int r = 0; r < 4; r++)
      #pragma unroll
      for (int m = 0; m < 4; m++) part[r][m] = 0.f;
    #pragma unroll
    for (int nb = 0; nb < 8; nb++){
      float g0 = geluf(acc2[nb][0]), g1 = geluf(acc2[nb][1]);
      float g2 = geluf(acc2[nb][2]), g3 = geluf(acc2[nb][3]);
      #pragma unroll
      for (int m = 0; m < 4; m++){
        float w = wbv[m][nb];
        part[0][m] += g0*w; part[1][m] += g1*w;
        part[2][m] += g2*w; part[3][m] += g3*w;
      }
    }
    #pragma unroll
    for (int s = 1; s < 16; s <<= 1)
      #pragma unroll
      for (int r = 0; r < 4; r++)
        #pragma unroll
        for (int m = 0; m < 4; m++)
          part[r][m] += __shfl_xor(part[r][m], s, 64);
    if (lrow == 0){
      #pragma unroll
      for (int r = 0; r < 4; r++){
        f32x4 tv = { part[r][0], part[r][1], part[r][2], part[r][3] };
        *(f32x4*)&T[(size_t)(tile*16 + kgrp*4 + r)*4] = tv;
      }
    }
  }
}

__global__ __launch_bounds__(1024) void k_scan(const int* __restrict__ deg, int* __restrict__ offs){
  __shared__ int wsum[16];
  __shared__ int sbase_s;
  const int tid = threadIdx.x, lane = tid & 63, wave = tid >> 6;
  if (tid == 0) sbase_s = 0;
  __syncthreads();
  for (int base = 0; base < NN; base += 4096){
    int i0 = base + tid*4;
    int v0=0,v1=0,v2=0,v3=0;
    if (i0+3 < NN){ int4 v = *(const int4*)(deg+i0); v0=v.x;v1=v.y;v2=v.z;v3=v.w; }
    else {
      if (i0   < NN) v0 = deg[i0];
      if (i0+1 < NN) v1 = deg[i0+1];
      if (i0+2 < NN) v2 = deg[i0+2];
    }
    int own = v0+v1+v2+v3;
    int inc = own;
    #pragma unroll
    for (int s=1;s<64;s<<=1){ int t = __shfl_up(inc, s, 64); if (lane >= s) inc += t; }
    if (lane == 63) wsum[wave] = inc;
    __syncthreads();
    if (wave == 0 && lane < 16){
      int w = wsum[lane];
      #pragma unroll
      for (int s=1;s<16;s<<=1){ int t = __shfl_up(w, s, 64); if (lane >= s) w += t; }
      wsum[lane] = w;
    }
    __syncthreads();
    int sbase = sbase_s;
    int wbase = sbase + (wave ? wsum[wave-1] : 0);
    int excl = wbase + inc - own;
    if (i0   < NN) offs[i0]   = excl;
    if (i0+1 < NN) offs[i0+1] = excl + v0;
    if (i0+2 < NN) offs[i0+2] = excl + v0+v1;
    if (i0+3 < NN) offs[i0+3] = excl + v0+v1+v2;
    __syncthreads();
    if (tid == 0) sbase_s = sbase + wsum[15];
    __syncthreads();
  }
  if (tid == 0) offs[NN] = sbase_s;
}

__global__ void k_fill(const int* __restrict__ src, const int* __restrict__ dst,
                       const int* __restrict__ offs, int* __restrict__ cur,
                       int* __restrict__ slist){
  int e = blockIdx.x*256 + threadIdx.x;
  if (e < NE){
    int d = dst[e];
    int p = atomicAdd(&cur[d], 1);
    slist[offs[d] + p] = src[e];
  }
}

// ------- K2b: per-node aggregation; scalarized (SGPR) edge indices -------
__global__ __launch_bounds__(256) void k_agg(const u16* __restrict__ Hb,
    const float* __restrict__ T, const int* __restrict__ offs,
    const int* __restrict__ slist, u16* __restrict__ GAb)
{
  const int lane = threadIdx.x & 63;
  const int wave = threadIdx.x >> 6;
  const int vo = lane*2;
  for (int v = blockIdx.x*4 + wave; v < NN; v += gridDim.x*4){
    const int e0 = __builtin_amdgcn_readfirstlane(offs[v]);
    const int e1 = __builtin_amdgcn_readfirstlane(offs[v+1]);
    float ax0=0, ax1=0, ax2=0, ax3=0;
    float ay0=0, ay1=0, ay2=0, ay3=0;
    float s0=0, s1=0, s2=0, s3=0;
    int idx = e0;
    for (; idx + 8 <= e1; idx += 8){
      unsigned pk[8]; float4 tt[8];
      #pragma unroll
      for (int u = 0; u < 8; u++){
        int sn = slist[idx+u];
        pk[u] = *(const unsigned*)(Hb + (size_t)sn*128 + vo);
        tt[u] = *(const float4*)(T + (size_t)sn*4);
      }
      #pragma unroll
      for (int u = 0; u < 8; u++){
        float hx = bfb2f((u16)(pk[u] & 0xffffu));
        float hy = bfb2f((u16)(pk[u] >> 16));
        ax0 += hx*tt[u].x; ax1 += hx*tt[u].y; ax2 += hx*tt[u].z; ax3 += hx*tt[u].w;
        ay0 += hy*tt[u].x; ay1 += hy*tt[u].y; ay2 += hy*tt[u].z; ay3 += hy*tt[u].w;
        s0 += tt[u].x; s1 += tt[u].y; s2 += tt[u].z; s3 += tt[u].w;
      }
    }
    for (; idx + 4 <= e1; idx += 4){
      unsigned pk[4]; float4 tt[4];
      #pragma unroll
      for (int u = 0; u < 4; u++){
        int sn = slist[idx+u];
        pk[u] = *(const unsigned*)(Hb + (size_t)sn*128 + vo);
        tt[u] = *(const float4*)(T + (size_t)sn*4);
      }
      #pragma unroll
      for (int u = 0; u < 4; u++){
        float hx = bfb2f((u16)(pk[u] & 0xffffu));
        float hy = bfb2f((u16)(pk[u] >> 16));
        ax0 += hx*tt[u].x; ax1 += hx*tt[u].y; ax2 += hx*tt[u].z; ax3 += hx*tt[u].w;
        ay0 += hy*tt[u].x; ay1 += hy*tt[u].y; ay2 += hy*tt[u].z; ay3 += hy*tt[u].w;
        s0 += tt[u].x; s1 += tt[u].y; s2 += tt[u].z; s3 += tt[u].w;
      }
    }
    for (; idx < e1; idx++){
      int sn = slist[idx];
      unsigned pk = *(const unsigned*)(Hb + (size_t)sn*128 + vo);
      float hx = bfb2f((u16)(pk & 0xffffu));
      float hy = bfb2f((u16)(pk >> 16));
      float4 wt = *(const float4*)(T + (size_t)sn*4);
      ax0 += hx*wt.x; ax1 += hx*wt.y; ax2 += hx*wt.z; ax3 += hx*wt.w;
      ay0 += hy*wt.x; ay1 += hy*wt.y; ay2 += hy*wt.z; ay3 += hy*wt.w;
      s0 += wt.x; s1 += wt.y; s2 += wt.z; s3 += wt.w;
    }
    float inv = 1.0f / fmaxf((float)(e1 - e0), 1.0f);
    float ox = geluf(ax0)*s0 + geluf(ax1)*s1 + geluf(ax2)*s2 + geluf(ax3)*s3;
    float oy = geluf(ay0)*s0 + geluf(ay1)*s1 + geluf(ay2)*s2 + geluf(ay3)*s3;
    ushort2 res;
    res.x = f2bfb(geluf(ox * inv));
    res.y = f2bfb(geluf(oy * inv));
    *(ushort2*)(GAb + (size_t)v*128 + vo) = res;
  }
}

// ------- K3 (MFMA, LDS-free, half-per-BLOCK for L1 reuse): out = [GAb, gelu(Hb)] @ W2^T + b2 -------
// block = {half, 4 consecutive tiles}; all 4 waves stream the SAME 32 KB half of W2r (fits L1).
__global__ __launch_bounds__(256, 4) void k_ff2(const u16* __restrict__ GAb,
    const u16* __restrict__ Hb, const u16* __restrict__ W2r,
    const float* __restrict__ b2, float* __restrict__ out)
{
  const int lane = threadIdx.x & 63;
  const int wave = threadIdx.x >> 6;      // 0..3
  const int lrow = lane & 15;
  const int kgrp = lane >> 4;
  const int nbh  = (blockIdx.x & 1)*4;    // which 4 nb-blocks (64 output cols) — same for whole block
  const int tile = (blockIdx.x >> 1)*4 + wave;
  if (tile >= NT) return;
  const int row = tile*16 + lrow;
  short8 a[8];
  {
    const u16* ga = GAb + (size_t)row*128 + kgrp*8;
    const u16* hb = Hb  + (size_t)row*128 + kgrp*8;
    #pragma unroll
    for (int kk = 0; kk < 4; kk++){
      a[kk]   = *(const short8*)(ga + kk*32);
      a[4+kk] = *(const short8*)(hb + kk*32);
    }
    #pragma unroll
    for (int kk = 4; kk < 8; kk++){
      union { short8 v; u16 u[8]; } g;
      #pragma unroll
      for (int j = 0; j < 8; j++)
        g.u[j] = f2bfb(geluf(bfb2f(((const u16*)&a[kk])[j])));
      a[kk] = g.v;
    }
  }
  f32x4 acc[4];
  #pragma unroll
  for (int q = 0; q < 4; q++) acc[q] = (f32x4){0.f,0.f,0.f,0.f};
  const u16* wbase = W2r + lane*8;
  #pragma unroll
  for (int kk = 0; kk < 8; kk++){
    #pragma unroll
    for (int q = 0; q < 4; q++){
      short8 bf = *(const short8*)(wbase + (size_t)((nbh + q)*8 + kk)*512);
      acc[q] = __builtin_amdgcn_mfma_f32_16x16x32_bf16(bf, a[kk], acc[q], 0, 0, 0);
    }
  }
  float* orp = out + (size_t)row*128 + nbh*16 + kgrp*4;
  #pragma unroll
  for (int q = 0; q < 4; q++){
    float4 bv = *(const float4*)(b2 + (nbh + q)*16 + kgrp*4);
    f32x4 o;
    o[0] = acc[q][0] + bv.x;
    o[1] = acc[q][1] + bv.y;
    o[2] = acc[q][2] + bv.z;
    o[3] = acc[q][3] + bv.w;
    *(f32x4*)(orp + q*16) = o;
  }
}

extern "C" void kernel_launch(void* const* d_in, const int* in_sizes, int n_in,
                              void* d_out, int out_size, void* d_ws, size_t ws_size,
                              hipStream_t stream)
{
  (void)in_sizes; (void)n_in; (void)out_size; (void)ws_size;
  const float* X  = (const float*)d_in[0];
  const int*   ei = (const int*)d_in[1];
  const float* W1 = (const float*)d_in[2];
  const float* b1 = (const float*)d_in[3];
  const float* WA = (const float*)d_in[4];
  const float* WB = (const float*)d_in[5];
  const float* W2 = (const float*)d_in[6];
  const float* b2 = (const float*)d_in[7];
  float* out = (float*)d_out;
  const int* src = ei;
  const int* dst = ei + NE;

  char* p = (char*)d_ws;
  u16*   Hb   = (u16*)(p);                 // 12,800,000 B
  u16*   GAb  = (u16*)(p + 12800000);      // 12,800,000 B
  float* T    = (float*)(p + 25600000);    //    800,000 B
  int*   deg  = (int*)(p + 26400000);      //    200,192 B
  int*   cur  = (int*)(p + 26600192);      //    200,192 B  (deg+cur zeroed by k_zero)
  int*   offs = (int*)(p + 26800384);      //    200,448 B
  int*   slist= (int*)(p + 27000832);      //  1,600,000 B
  u16*   W1b  = (u16*)(p + 28600832);      //     32,768 B
  u16*   WAb  = (u16*)(p + 28633600);      //     32,768 B
  u16*   W2r  = (u16*)(p + 28666368);      //     65,536 B  (total ~28.7 MB)

  (void)hipFuncSetAttribute((const void*)k_ff1n, hipFuncAttributeMaxDynamicSharedMemorySize, 104448);

  k_zero<<<98, 256, 0, stream>>>((int4*)deg);
  k_pre <<<48 + (NE+255)/256, 256, 0, stream>>>(W1, WA, W2, W1b, WAb, W2r, dst, deg);
  k_ff1n<<<391, 512, 104448, stream>>>(X, W1b, b1, WAb, WB, Hb, T);
  k_scan<<<1, 1024, 0, stream>>>(deg, offs);
  k_fill<<<(NE+255)/256, 256, 0, stream>>>(src, dst, offs, cur, slist);
  k_agg <<<2048, 256, 0, stream>>>(Hb, T, offs, slist, GAb);
  k_ff2 <<<2*((NT+3)/4), 256, 0, stream>>>(GAb, Hb, W2r, b2, out);
}